// Round 1
// baseline (599.534 us; speedup 1.0000x reference)
//
#include <hip/hip_runtime.h>
#include <hip/hip_bf16.h>
#include <float.h>

#define B_SZ 8192
#define D_SZ 1024
#define C_SZ 256
#define MARGIN 0.2f
#define THRESH 0.5f

typedef __attribute__((ext_vector_type(8))) short short8;
typedef __attribute__((ext_vector_type(4))) float f32x4;

// ---------------- workspace layout (bytes) ----------------
#define OFF_IMG   ((size_t)0)                       // 8192*1024*2 = 16,777,216
#define OFF_TXT   ((size_t)16777216)                // 16,777,216
#define OFF_CPT   ((size_t)33554432)                // 8192*256*2 = 4,194,304
#define OFF_HN    ((size_t)37748736)                // 8192*4
#define OFF_VALID ((size_t)37781504)                // 8192 bytes
#define OFF_PMAX  ((size_t)37814272)                // 64*8192*4 = 2,097,152
#define OFF_PPOS  ((size_t)39911424)                // 64*8192   =   524,288
#define OFF_PNEG  ((size_t)40435712)                // 64*8192   =   524,288
#define OFF_ACC   ((size_t)40960000)                // 16 bytes (sum, cnt)

// ---------------- fp32 -> bf16 conversion ----------------
__global__ __launch_bounds__(256) void conv_kernel(
    const float* __restrict__ img, const float* __restrict__ txt,
    const float* __restrict__ cpt,
    __hip_bfloat16* __restrict__ imgB, __hip_bfloat16* __restrict__ txtB,
    __hip_bfloat16* __restrict__ cptB)
{
    const size_t NI = (size_t)B_SZ * D_SZ / 4;   // float4 chunks
    const size_t NT = NI;
    size_t tid = (size_t)blockIdx.x * blockDim.x + threadIdx.x;
    const float* src; __hip_bfloat16* dst; size_t off;
    if (tid < NI)           { src = img; dst = imgB; off = tid; }
    else if (tid < NI + NT) { src = txt; dst = txtB; off = tid - NI; }
    else                    { src = cpt; dst = cptB; off = tid - NI - NT; }
    float4 v = ((const float4*)src)[off];
    union { ushort4 u; __hip_bfloat162 h[2]; } o;
    o.h[0] = __float22bfloat162_rn(make_float2(v.x, v.y));
    o.h[1] = __float22bfloat162_rn(make_float2(v.z, v.w));
    ((ushort4*)dst)[off] = o.u;
}

// ---------------- async global->LDS 16B ----------------
__device__ __forceinline__ void async_copy16(const void* g, void* l) {
    __builtin_amdgcn_global_load_lds(
        (const __attribute__((address_space(1))) void*)g,
        (__attribute__((address_space(3))) void*)l, 16, 0, 0);
}

// Stage a 128x32 bf16 tile (row-major, contiguous 64B rows) into LDS.
// gsrc points at tile origin (row0*ldk + k0 already applied), ldk in elements.
__device__ __forceinline__ void stage_tile(const __hip_bfloat16* __restrict__ gsrc,
                                           int ldk, short* lds, int w, int lane)
{
#pragma unroll
    for (int c = 0; c < 2; ++c) {
        int q = (w * 2 + c) * 64 + lane;                       // 16B chunk id, 0..511
        const __hip_bfloat16* g = gsrc + (size_t)(q >> 2) * ldk + (q & 3) * 8;
        void* l = (void*)(lds + (w * 2 + c) * 512);            // wave-uniform base
        async_copy16(g, l);
    }
}

// ---------------- fused tile kernel (PASS=1: mine, PASS=2: hinge) ----------------
template <int PASS>
__global__ __launch_bounds__(256) void tile_kernel(
    const __hip_bfloat16* __restrict__ imgB,
    const __hip_bfloat16* __restrict__ txtB,
    const __hip_bfloat16* __restrict__ cptB,
    float* __restrict__ pmax, unsigned char* __restrict__ ppos,
    unsigned char* __restrict__ pneg,
    const float* __restrict__ hn, const unsigned char* __restrict__ validv,
    float* __restrict__ accsum, unsigned int* __restrict__ acccnt)
{
    __shared__ short As[128 * 32];
    __shared__ short Bs[128 * 32];
    __shared__ float eps_max[2][128];
    __shared__ unsigned int eps_pos[2][128];
    __shared__ unsigned int eps_neg[2][128];
    __shared__ float hnS[128];
    __shared__ unsigned char valS[128];
    __shared__ float redS[4];
    __shared__ unsigned int redC[4];

    const int tid  = threadIdx.x;
    const int lane = tid & 63;
    const int w    = tid >> 6;       // wave 0..3
    const int wr   = w >> 1;         // wave row (0..1)
    const int wc   = w & 1;          // wave col (0..1)
    const int quad = lane >> 4;
    const int l15  = lane & 15;

    const int ct = blockIdx.x, rt = blockIdx.y;
    const int r0 = rt * 128, c0 = ct * 128;

    if (PASS == 2 && tid < 128) {
        hnS[tid]  = hn[r0 + tid];
        valS[tid] = validv[r0 + tid];
    }

    f32x4 acc[4][4];
#pragma unroll
    for (int mt = 0; mt < 4; ++mt)
#pragma unroll
        for (int nt = 0; nt < 4; ++nt)
            acc[mt][nt] = (f32x4){0.f, 0.f, 0.f, 0.f};

    // -------- gram = concept @ concept^T, K = 256 --------
    for (int kb = 0; kb < C_SZ; kb += 32) {
        __syncthreads();
        stage_tile(cptB + (size_t)r0 * C_SZ + kb, C_SZ, As, w, lane);
        stage_tile(cptB + (size_t)c0 * C_SZ + kb, C_SZ, Bs, w, lane);
        __syncthreads();
        short8 af[4], bf[4];
#pragma unroll
        for (int mt = 0; mt < 4; ++mt)
            af[mt] = *(const short8*)(As + (wr * 64 + mt * 16 + l15) * 32 + quad * 8);
#pragma unroll
        for (int nt = 0; nt < 4; ++nt)
            bf[nt] = *(const short8*)(Bs + (wc * 64 + nt * 16 + l15) * 32 + quad * 8);
#pragma unroll
        for (int mt = 0; mt < 4; ++mt)
#pragma unroll
            for (int nt = 0; nt < 4; ++nt)
                acc[mt][nt] = __builtin_amdgcn_mfma_f32_16x16x32_bf16(
                    af[mt], bf[nt], acc[mt][nt], 0, 0, 0);
    }

    // pos bits: gram > 0.5 and off-diagonal. bit = mt*16 + nt*4 + r
    unsigned long long posbits = 0ull;
#pragma unroll
    for (int mt = 0; mt < 4; ++mt)
#pragma unroll
        for (int nt = 0; nt < 4; ++nt)
#pragma unroll
            for (int r = 0; r < 4; ++r) {
                int grow = r0 + wr * 64 + mt * 16 + quad * 4 + r;
                int gcol = c0 + wc * 64 + nt * 16 + l15;
                int pos = (acc[mt][nt][r] > THRESH) & (grow != gcol);
                posbits |= ((unsigned long long)pos) << (mt * 16 + nt * 4 + r);
            }

    // -------- sim = image @ text^T, K = 1024 --------
#pragma unroll
    for (int mt = 0; mt < 4; ++mt)
#pragma unroll
        for (int nt = 0; nt < 4; ++nt)
            acc[mt][nt] = (f32x4){0.f, 0.f, 0.f, 0.f};

    for (int kb = 0; kb < D_SZ; kb += 32) {
        __syncthreads();
        stage_tile(imgB + (size_t)r0 * D_SZ + kb, D_SZ, As, w, lane);
        stage_tile(txtB + (size_t)c0 * D_SZ + kb, D_SZ, Bs, w, lane);
        __syncthreads();
        short8 af[4], bf[4];
#pragma unroll
        for (int mt = 0; mt < 4; ++mt)
            af[mt] = *(const short8*)(As + (wr * 64 + mt * 16 + l15) * 32 + quad * 8);
#pragma unroll
        for (int nt = 0; nt < 4; ++nt)
            bf[nt] = *(const short8*)(Bs + (wc * 64 + nt * 16 + l15) * 32 + quad * 8);
#pragma unroll
        for (int mt = 0; mt < 4; ++mt)
#pragma unroll
            for (int nt = 0; nt < 4; ++nt)
                acc[mt][nt] = __builtin_amdgcn_mfma_f32_16x16x32_bf16(
                    af[mt], bf[nt], acc[mt][nt], 0, 0, 0);
    }

    if (PASS == 1) {
        // per-row (within tile): max sim over negatives, any-pos, any-neg
#pragma unroll
        for (int mt = 0; mt < 4; ++mt)
#pragma unroll
            for (int r = 0; r < 4; ++r) {
                float rowm = -FLT_MAX;
                int rp = 0, rn = 0;
                int grow = r0 + wr * 64 + mt * 16 + quad * 4 + r;
#pragma unroll
                for (int nt = 0; nt < 4; ++nt) {
                    int bit  = mt * 16 + nt * 4 + r;
                    int pos  = (int)((posbits >> bit) & 1ull);
                    int gcol = c0 + wc * 64 + nt * 16 + l15;
                    int diag = (grow == gcol);
                    int neg  = (!pos) & (!diag);
                    float s  = acc[mt][nt][r];
                    rowm = neg ? fmaxf(rowm, s) : rowm;
                    rp |= pos; rn |= neg;
                }
                // reduce across the 16 lanes of this quad (same rows, diff cols)
#pragma unroll
                for (int m = 1; m < 16; m <<= 1) {
                    rowm = fmaxf(rowm, __shfl_xor(rowm, m));
                    rp |= __shfl_xor(rp, m);
                    rn |= __shfl_xor(rn, m);
                }
                if (l15 == 0) {
                    int rl = wr * 64 + mt * 16 + quad * 4 + r;
                    eps_max[wc][rl] = rowm;
                    eps_pos[wc][rl] = (unsigned int)rp;
                    eps_neg[wc][rl] = (unsigned int)rn;
                }
            }
        __syncthreads();
        if (tid < 128) {
            float m = fmaxf(eps_max[0][tid], eps_max[1][tid]);
            unsigned int p = eps_pos[0][tid] | eps_pos[1][tid];
            unsigned int n = eps_neg[0][tid] | eps_neg[1][tid];
            size_t idx = (size_t)ct * B_SZ + (r0 + tid);
            pmax[idx] = m;
            ppos[idx] = (unsigned char)(p ? 1 : 0);
            pneg[idx] = (unsigned char)(n ? 1 : 0);
        }
    } else {
        // hinge accumulation over pos & valid
        float lsum = 0.f;
        unsigned int lcnt = 0;
#pragma unroll
        for (int mt = 0; mt < 4; ++mt)
#pragma unroll
            for (int r = 0; r < 4; ++r) {
                int rl = wr * 64 + mt * 16 + quad * 4 + r;
                float hni = hnS[rl];
                int v = (int)valS[rl];
#pragma unroll
                for (int nt = 0; nt < 4; ++nt) {
                    int bit = mt * 16 + nt * 4 + r;
                    int on  = ((int)((posbits >> bit) & 1ull)) & v;
                    float h = fmaxf(MARGIN - acc[mt][nt][r] + hni, 0.f);
                    lsum += h * (float)on;
                    lcnt += (unsigned int)on;
                }
            }
        // wave reduce (64 lanes)
#pragma unroll
        for (int off = 32; off > 0; off >>= 1) {
            lsum += __shfl_down(lsum, off);
            lcnt += (unsigned int)__shfl_down((int)lcnt, off);
        }
        if (lane == 0) { redS[w] = lsum; redC[w] = lcnt; }
        __syncthreads();
        if (tid == 0) {
            float s = redS[0] + redS[1] + redS[2] + redS[3];
            unsigned int c = redC[0] + redC[1] + redC[2] + redC[3];
            atomicAdd(accsum, s);
            atomicAdd(acccnt, c);
        }
    }
}

// ---------------- per-row partial reduce ----------------
__global__ __launch_bounds__(256) void reduce_kernel(
    const float* __restrict__ pmax, const unsigned char* __restrict__ ppos,
    const unsigned char* __restrict__ pneg,
    float* __restrict__ hn, unsigned char* __restrict__ validv)
{
    int row = blockIdx.x * blockDim.x + threadIdx.x;
    if (row >= B_SZ) return;
    float m = -FLT_MAX;
    int hp = 0, hnn = 0;
    for (int ct = 0; ct < 64; ++ct) {
        size_t idx = (size_t)ct * B_SZ + row;
        m = fmaxf(m, pmax[idx]);
        hp  |= ppos[idx];
        hnn |= pneg[idx];
    }
    int valid = (hp && hnn) ? 1 : 0;
    hn[row] = valid ? m : 0.0f;
    validv[row] = (unsigned char)valid;
}

// ---------------- finalize ----------------
__global__ void final_kernel(const float* __restrict__ accsum,
                             const unsigned int* __restrict__ acccnt,
                             float* __restrict__ out)
{
    float s = accsum[0];
    unsigned int c = acccnt[0];
    out[0] = (c > 0) ? (s / (float)c) : 0.0f;
}

extern "C" void kernel_launch(void* const* d_in, const int* in_sizes, int n_in,
                              void* d_out, int out_size, void* d_ws, size_t ws_size,
                              hipStream_t stream)
{
    const float* img = (const float*)d_in[0];   // [8192,1024]
    const float* txt = (const float*)d_in[1];   // [8192,1024]
    const float* cpt = (const float*)d_in[2];   // [8192,256]
    float* out = (float*)d_out;

    char* ws = (char*)d_ws;
    __hip_bfloat16* imgB = (__hip_bfloat16*)(ws + OFF_IMG);
    __hip_bfloat16* txtB = (__hip_bfloat16*)(ws + OFF_TXT);
    __hip_bfloat16* cptB = (__hip_bfloat16*)(ws + OFF_CPT);
    float* hn            = (float*)(ws + OFF_HN);
    unsigned char* valid = (unsigned char*)(ws + OFF_VALID);
    float* pmax          = (float*)(ws + OFF_PMAX);
    unsigned char* ppos  = (unsigned char*)(ws + OFF_PPOS);
    unsigned char* pneg  = (unsigned char*)(ws + OFF_PNEG);
    float* accsum        = (float*)(ws + OFF_ACC);
    unsigned int* acccnt = (unsigned int*)(ws + OFF_ACC + 4);

    hipMemsetAsync(ws + OFF_ACC, 0, 16, stream);

    // fp32 -> bf16: (8192*1024*2 + 8192*256) / 4 float4s = 4,718,592 threads
    conv_kernel<<<18432, 256, 0, stream>>>(img, txt, cpt, imgB, txtB, cptB);

    dim3 grid(64, 64);
    tile_kernel<1><<<grid, 256, 0, stream>>>(imgB, txtB, cptB, pmax, ppos, pneg,
                                             hn, valid, accsum, acccnt);
    reduce_kernel<<<32, 256, 0, stream>>>(pmax, ppos, pneg, hn, valid);
    tile_kernel<2><<<grid, 256, 0, stream>>>(imgB, txtB, cptB, pmax, ppos, pneg,
                                             hn, valid, accsum, acccnt);
    final_kernel<<<1, 1, 0, stream>>>(accsum, acccnt, out);
}

// Round 2
// 426.113 us; speedup vs baseline: 1.4070x; 1.4070x over previous
//
#include <hip/hip_runtime.h>
#include <hip/hip_bf16.h>
#include <float.h>

#define B_SZ 8192
#define D_SZ 1024
#define C_SZ 256
#define MARGIN 0.2f
#define THRESH 0.5f

typedef __attribute__((ext_vector_type(8))) short short8;
typedef __attribute__((ext_vector_type(4))) float f32x4;

// ---------------- workspace layout (bytes) ----------------
#define OFF_IMG   ((size_t)0)                       // 8192*1024*2 = 16,777,216
#define OFF_TXT   ((size_t)16777216)                // 16,777,216
#define OFF_CPT   ((size_t)33554432)                // 8192*256*2 = 4,194,304
#define OFF_HN    ((size_t)37748736)                // 8192*4
#define OFF_VALID ((size_t)37781504)                // 8192 bytes
#define OFF_PMAX  ((size_t)37814272)                // 64*8192*4 = 2,097,152
#define OFF_PPOS  ((size_t)39911424)                // 64*8192   =   524,288
#define OFF_PNEG  ((size_t)40435712)                // 64*8192   =   524,288
#define OFF_ACC   ((size_t)40960000)                // 16 bytes (sum, cnt)
#define OFF_SIM   ((size_t)40960512)                // 8192*8192*2 = 134,217,728 (masked sim, bf16)

#define INF_BF16_BITS ((unsigned short)0x7F80)

// ---------------- fp32 -> bf16 conversion ----------------
__global__ __launch_bounds__(256) void conv_kernel(
    const float* __restrict__ img, const float* __restrict__ txt,
    const float* __restrict__ cpt,
    __hip_bfloat16* __restrict__ imgB, __hip_bfloat16* __restrict__ txtB,
    __hip_bfloat16* __restrict__ cptB)
{
    const size_t NI = (size_t)B_SZ * D_SZ / 4;   // float4 chunks
    const size_t NT = NI;
    size_t tid = (size_t)blockIdx.x * blockDim.x + threadIdx.x;
    const float* src; __hip_bfloat16* dst; size_t off;
    if (tid < NI)           { src = img; dst = imgB; off = tid; }
    else if (tid < NI + NT) { src = txt; dst = txtB; off = tid - NI; }
    else                    { src = cpt; dst = cptB; off = tid - NI - NT; }
    float4 v = ((const float4*)src)[off];
    union { ushort4 u; __hip_bfloat162 h[2]; } o;
    o.h[0] = __float22bfloat162_rn(make_float2(v.x, v.y));
    o.h[1] = __float22bfloat162_rn(make_float2(v.z, v.w));
    ((ushort4*)dst)[off] = o.u;
}

// ---------------- async global->LDS 16B ----------------
__device__ __forceinline__ void async_copy16(const void* g, void* l) {
    __builtin_amdgcn_global_load_lds(
        (const __attribute__((address_space(1))) void*)g,
        (__attribute__((address_space(3))) void*)l, 16, 0, 0);
}

// Stage a 128x32 bf16 tile into LDS with XOR bank swizzle.
// LDS chunk c (16B) holds global chunk (row = c>>2, kq = (c&3) ^ ((row>>1)&3)).
// Fragment readers must apply the same swizzle. global_load_lds writes stay
// contiguous (wave-uniform base + lane*16) — we permute the global source.
__device__ __forceinline__ void stage_tile(const __hip_bfloat16* __restrict__ gsrc,
                                           int ldk, short* lds, int w, int lane)
{
#pragma unroll
    for (int c = 0; c < 2; ++c) {
        int q  = (w * 2 + c) * 64 + lane;              // LDS 16B chunk id, 0..511
        int gr = q >> 2;
        int gq = (q & 3) ^ ((gr >> 1) & 3);            // swizzled k-quad
        const __hip_bfloat16* g = gsrc + (size_t)gr * ldk + gq * 8;
        void* l = (void*)(lds + (w * 2 + c) * 512);    // wave-uniform base
        async_copy16(g, l);
    }
}

// ---------------- fused tile kernel: gram mask + sim + mine + store ----------------
__global__ __launch_bounds__(256) void tile_kernel(
    const __hip_bfloat16* __restrict__ imgB,
    const __hip_bfloat16* __restrict__ txtB,
    const __hip_bfloat16* __restrict__ cptB,
    float* __restrict__ pmax, unsigned char* __restrict__ ppos,
    unsigned char* __restrict__ pneg,
    unsigned short* __restrict__ simM)
{
    __shared__ short As[128 * 32];
    __shared__ short Bs[128 * 32];
    __shared__ float eps_max[2][128];
    __shared__ unsigned int eps_pos[2][128];
    __shared__ unsigned int eps_neg[2][128];

    const int tid  = threadIdx.x;
    const int lane = tid & 63;
    const int w    = tid >> 6;       // wave 0..3
    const int wr   = w >> 1;         // wave row (0..1)
    const int wc   = w & 1;          // wave col (0..1)
    const int quad = lane >> 4;
    const int l15  = lane & 15;
    const int sw   = (l15 >> 1) & 3; // read-side swizzle term (row bits 1..2)

    const int ct = blockIdx.x, rt = blockIdx.y;
    const int r0 = rt * 128, c0 = ct * 128;

    f32x4 acc[4][4];
#pragma unroll
    for (int mt = 0; mt < 4; ++mt)
#pragma unroll
        for (int nt = 0; nt < 4; ++nt)
            acc[mt][nt] = (f32x4){0.f, 0.f, 0.f, 0.f};

    // -------- gram = concept @ concept^T, K = 256 --------
    for (int kb = 0; kb < C_SZ; kb += 32) {
        __syncthreads();
        stage_tile(cptB + (size_t)r0 * C_SZ + kb, C_SZ, As, w, lane);
        stage_tile(cptB + (size_t)c0 * C_SZ + kb, C_SZ, Bs, w, lane);
        __syncthreads();
        short8 af[4], bf[4];
#pragma unroll
        for (int mt = 0; mt < 4; ++mt)
            af[mt] = *(const short8*)(As + ((wr * 64 + mt * 16 + l15) * 4 + (quad ^ sw)) * 8);
#pragma unroll
        for (int nt = 0; nt < 4; ++nt)
            bf[nt] = *(const short8*)(Bs + ((wc * 64 + nt * 16 + l15) * 4 + (quad ^ sw)) * 8);
#pragma unroll
        for (int mt = 0; mt < 4; ++mt)
#pragma unroll
            for (int nt = 0; nt < 4; ++nt)
                acc[mt][nt] = __builtin_amdgcn_mfma_f32_16x16x32_bf16(
                    af[mt], bf[nt], acc[mt][nt], 0, 0, 0);
    }

    // pos bits: gram > 0.5 and off-diagonal. bit = mt*16 + nt*4 + r
    unsigned long long posbits = 0ull;
#pragma unroll
    for (int mt = 0; mt < 4; ++mt)
#pragma unroll
        for (int nt = 0; nt < 4; ++nt)
#pragma unroll
            for (int r = 0; r < 4; ++r) {
                int grow = r0 + wr * 64 + mt * 16 + quad * 4 + r;
                int gcol = c0 + wc * 64 + nt * 16 + l15;
                int pos = (acc[mt][nt][r] > THRESH) & (grow != gcol);
                posbits |= ((unsigned long long)pos) << (mt * 16 + nt * 4 + r);
            }

    // -------- sim = image @ text^T, K = 1024 --------
#pragma unroll
    for (int mt = 0; mt < 4; ++mt)
#pragma unroll
        for (int nt = 0; nt < 4; ++nt)
            acc[mt][nt] = (f32x4){0.f, 0.f, 0.f, 0.f};

    for (int kb = 0; kb < D_SZ; kb += 32) {
        __syncthreads();
        stage_tile(imgB + (size_t)r0 * D_SZ + kb, D_SZ, As, w, lane);
        stage_tile(txtB + (size_t)c0 * D_SZ + kb, D_SZ, Bs, w, lane);
        __syncthreads();
        short8 af[4], bf[4];
#pragma unroll
        for (int mt = 0; mt < 4; ++mt)
            af[mt] = *(const short8*)(As + ((wr * 64 + mt * 16 + l15) * 4 + (quad ^ sw)) * 8);
#pragma unroll
        for (int nt = 0; nt < 4; ++nt)
            bf[nt] = *(const short8*)(Bs + ((wc * 64 + nt * 16 + l15) * 4 + (quad ^ sw)) * 8);
#pragma unroll
        for (int mt = 0; mt < 4; ++mt)
#pragma unroll
            for (int nt = 0; nt < 4; ++nt)
                acc[mt][nt] = __builtin_amdgcn_mfma_f32_16x16x32_bf16(
                    af[mt], bf[nt], acc[mt][nt], 0, 0, 0);
    }

    // -------- epilogue: mine neg-max / any-pos / any-neg, store masked sim --------
#pragma unroll
    for (int mt = 0; mt < 4; ++mt)
#pragma unroll
        for (int r = 0; r < 4; ++r) {
            float rowm = -FLT_MAX;
            int rp = 0, rn = 0;
            int grow = r0 + wr * 64 + mt * 16 + quad * 4 + r;
#pragma unroll
            for (int nt = 0; nt < 4; ++nt) {
                int bit  = mt * 16 + nt * 4 + r;
                int pos  = (int)((posbits >> bit) & 1ull);
                int gcol = c0 + wc * 64 + nt * 16 + l15;
                int diag = (grow == gcol);
                int neg  = (!pos) & (!diag);
                float s  = acc[mt][nt][r];
                rowm = neg ? fmaxf(rowm, s) : rowm;
                rp |= pos; rn |= neg;
                // masked sim: pos ? bf16(sim) : +inf (sentinel encodes the mask)
                float mv = pos ? s : __builtin_inff();
                __hip_bfloat16 hb = __float2bfloat16(mv);
                simM[(size_t)grow * B_SZ + gcol] = *(unsigned short*)&hb;
            }
            // reduce across the 16 lanes of this quad (same rows, diff cols)
#pragma unroll
            for (int m = 1; m < 16; m <<= 1) {
                rowm = fmaxf(rowm, __shfl_xor(rowm, m));
                rp |= __shfl_xor(rp, m);
                rn |= __shfl_xor(rn, m);
            }
            if (l15 == 0) {
                int rl = wr * 64 + mt * 16 + quad * 4 + r;
                eps_max[wc][rl] = rowm;
                eps_pos[wc][rl] = (unsigned int)rp;
                eps_neg[wc][rl] = (unsigned int)rn;
            }
        }
    __syncthreads();
    if (tid < 128) {
        float m = fmaxf(eps_max[0][tid], eps_max[1][tid]);
        unsigned int p = eps_pos[0][tid] | eps_pos[1][tid];
        unsigned int n = eps_neg[0][tid] | eps_neg[1][tid];
        size_t idx = (size_t)ct * B_SZ + (r0 + tid);
        pmax[idx] = m;
        ppos[idx] = (unsigned char)(p ? 1 : 0);
        pneg[idx] = (unsigned char)(n ? 1 : 0);
    }
}

// ---------------- per-row partial reduce ----------------
__global__ __launch_bounds__(256) void reduce_kernel(
    const float* __restrict__ pmax, const unsigned char* __restrict__ ppos,
    const unsigned char* __restrict__ pneg,
    float* __restrict__ hn, unsigned char* __restrict__ validv)
{
    int row = blockIdx.x * blockDim.x + threadIdx.x;
    if (row >= B_SZ) return;
    float m = -FLT_MAX;
    int hp = 0, hnn = 0;
    for (int ct = 0; ct < 64; ++ct) {
        size_t idx = (size_t)ct * B_SZ + row;
        m = fmaxf(m, pmax[idx]);
        hp  |= ppos[idx];
        hnn |= pneg[idx];
    }
    int valid = (hp && hnn) ? 1 : 0;
    hn[row] = valid ? m : 0.0f;
    validv[row] = (unsigned char)valid;
}

// ---------------- streaming hinge over masked sim ----------------
__global__ __launch_bounds__(256) void hinge_kernel(
    const unsigned short* __restrict__ simM,
    const float* __restrict__ hn, const unsigned char* __restrict__ validv,
    float* __restrict__ accsum, unsigned int* __restrict__ acccnt)
{
    __shared__ float redS[4];
    __shared__ unsigned int redC[4];
    const size_t N8 = (size_t)B_SZ * B_SZ / 8;   // 16B (8 bf16) chunks
    const size_t stride = (size_t)gridDim.x * blockDim.x;
    float lsum = 0.f;
    unsigned int lcnt = 0;
    for (size_t i = (size_t)blockIdx.x * blockDim.x + threadIdx.x; i < N8; i += stride) {
        int row = (int)(i >> 10);                 // 1024 chunks per row
        float hv = hn[row];
        int v = (int)validv[row];
        ushort4 c0 = ((const ushort4*)simM)[i * 2];
        ushort4 c1 = ((const ushort4*)simM)[i * 2 + 1];
        unsigned short e[8] = {c0.x, c0.y, c0.z, c0.w, c1.x, c1.y, c1.z, c1.w};
#pragma unroll
        for (int j = 0; j < 8; ++j) {
            int on = (e[j] != INF_BF16_BITS) & v;
            float s = __uint_as_float(((unsigned int)e[j]) << 16);
            float h = fmaxf(MARGIN - s + hv, 0.f);
            lsum += on ? h : 0.f;
            lcnt += (unsigned int)on;
        }
    }
    const int lane = threadIdx.x & 63;
    const int w    = threadIdx.x >> 6;
#pragma unroll
    for (int off = 32; off > 0; off >>= 1) {
        lsum += __shfl_down(lsum, off);
        lcnt += (unsigned int)__shfl_down((int)lcnt, off);
    }
    if (lane == 0) { redS[w] = lsum; redC[w] = lcnt; }
    __syncthreads();
    if (threadIdx.x == 0) {
        atomicAdd(accsum, redS[0] + redS[1] + redS[2] + redS[3]);
        atomicAdd(acccnt, redC[0] + redC[1] + redC[2] + redC[3]);
    }
}

// ---------------- finalize ----------------
__global__ void final_kernel(const float* __restrict__ accsum,
                             const unsigned int* __restrict__ acccnt,
                             float* __restrict__ out)
{
    float s = accsum[0];
    unsigned int c = acccnt[0];
    out[0] = (c > 0) ? (s / (float)c) : 0.0f;
}

extern "C" void kernel_launch(void* const* d_in, const int* in_sizes, int n_in,
                              void* d_out, int out_size, void* d_ws, size_t ws_size,
                              hipStream_t stream)
{
    const float* img = (const float*)d_in[0];   // [8192,1024]
    const float* txt = (const float*)d_in[1];   // [8192,1024]
    const float* cpt = (const float*)d_in[2];   // [8192,256]
    float* out = (float*)d_out;

    char* ws = (char*)d_ws;
    __hip_bfloat16* imgB = (__hip_bfloat16*)(ws + OFF_IMG);
    __hip_bfloat16* txtB = (__hip_bfloat16*)(ws + OFF_TXT);
    __hip_bfloat16* cptB = (__hip_bfloat16*)(ws + OFF_CPT);
    float* hn            = (float*)(ws + OFF_HN);
    unsigned char* valid = (unsigned char*)(ws + OFF_VALID);
    float* pmax          = (float*)(ws + OFF_PMAX);
    unsigned char* ppos  = (unsigned char*)(ws + OFF_PPOS);
    unsigned char* pneg  = (unsigned char*)(ws + OFF_PNEG);
    float* accsum        = (float*)(ws + OFF_ACC);
    unsigned int* acccnt = (unsigned int*)(ws + OFF_ACC + 4);
    unsigned short* simM = (unsigned short*)(ws + OFF_SIM);

    hipMemsetAsync(ws + OFF_ACC, 0, 16, stream);

    // fp32 -> bf16: (8192*1024*2 + 8192*256) / 4 float4s = 4,718,592 threads
    conv_kernel<<<18432, 256, 0, stream>>>(img, txt, cpt, imgB, txtB, cptB);

    dim3 grid(64, 64);
    tile_kernel<<<grid, 256, 0, stream>>>(imgB, txtB, cptB, pmax, ppos, pneg, simM);
    reduce_kernel<<<32, 256, 0, stream>>>(pmax, ppos, pneg, hn, valid);
    hinge_kernel<<<2048, 256, 0, stream>>>(simM, hn, valid, accsum, acccnt);
    final_kernel<<<1, 1, 0, stream>>>(accsum, acccnt, out);
}

// Round 3
// 372.330 us; speedup vs baseline: 1.6102x; 1.1445x over previous
//
#include <hip/hip_runtime.h>
#include <hip/hip_bf16.h>
#include <hip/hip_fp8.h>
#include <float.h>

#define B_SZ 8192
#define D_SZ 1024          // bytes per row of img/txt in fp8 (= elements)
#define C_SZ 256           // bytes per row of concept in fp8
#define MARGIN 0.2f
#define THRESH 0.5f
#define SCALE1 0x7F7F7F7F  // E8M0 = 127 -> 2^0 = 1.0 in all 4 bytes

typedef __attribute__((ext_vector_type(8)))  int   int8v;
typedef __attribute__((ext_vector_type(16))) float f32x16;

// ---------------- workspace layout (bytes) ----------------
#define OFF_IMG   ((size_t)0)           // 8192*1024 = 8,388,608
#define OFF_TXT   ((size_t)8388608)     // 8,388,608
#define OFF_CPT   ((size_t)16777216)    // 8192*256 = 2,097,152
#define OFF_HN    ((size_t)18874368)    // 8192*4
#define OFF_VALID ((size_t)18907136)    // 8192
#define OFF_PMAX  ((size_t)18915328)    // 64*8192*4 = 2,097,152
#define OFF_PPOS  ((size_t)21012480)    // 64*8192
#define OFF_PNEG  ((size_t)21536768)    // 64*8192
#define OFF_ACC   ((size_t)22061056)    // 16 bytes (sum, cnt)
#define OFF_SIM   ((size_t)22061568)    // 8192*8192*2 = 134,217,728 (masked sim, bf16)

#define INF_BF16_BITS ((unsigned short)0x7F80)

// ---------------- fp32 -> fp8 e4m3 (OCP) conversion ----------------
// 8 floats -> 8 bytes per thread.
__global__ __launch_bounds__(256) void conv_kernel(
    const float* __restrict__ img, const float* __restrict__ txt,
    const float* __restrict__ cpt,
    unsigned char* __restrict__ imgF, unsigned char* __restrict__ txtF,
    unsigned char* __restrict__ cptF)
{
    const size_t NI = (size_t)B_SZ * D_SZ / 8;   // 8-float chunks: 1,048,576
    size_t tid = (size_t)blockIdx.x * blockDim.x + threadIdx.x;
    const float* src; unsigned char* dst; size_t off;
    if (tid < NI)           { src = img; dst = imgF; off = tid; }
    else if (tid < 2 * NI)  { src = txt; dst = txtF; off = tid - NI; }
    else                    { src = cpt; dst = cptF; off = tid - 2 * NI; }
    float4 a = ((const float4*)src)[off * 2];
    float4 b = ((const float4*)src)[off * 2 + 1];
    unsigned int lo =  (unsigned int)__hip_fp8_e4m3(a.x).__x
                    | ((unsigned int)__hip_fp8_e4m3(a.y).__x << 8)
                    | ((unsigned int)__hip_fp8_e4m3(a.z).__x << 16)
                    | ((unsigned int)__hip_fp8_e4m3(a.w).__x << 24);
    unsigned int hi =  (unsigned int)__hip_fp8_e4m3(b.x).__x
                    | ((unsigned int)__hip_fp8_e4m3(b.y).__x << 8)
                    | ((unsigned int)__hip_fp8_e4m3(b.z).__x << 16)
                    | ((unsigned int)__hip_fp8_e4m3(b.w).__x << 24);
    ((uint2*)dst)[off] = make_uint2(lo, hi);
}

// ---------------- async global->LDS 16B ----------------
__device__ __forceinline__ void async_copy16(const void* g, void* l) {
    __builtin_amdgcn_global_load_lds(
        (const __attribute__((address_space(1))) void*)g,
        (__attribute__((address_space(3))) void*)l, 16, 0, 0);
}

// Stage a 128x128B fp8 tile into LDS with XOR chunk swizzle.
// LDS 16B-chunk c holds global chunk (row = c>>3, cq = (c&7) ^ (row&7)).
// global_load_lds dest stays wave-uniform base + lane*16 (m104/m108 rule);
// the permutation is applied on the global source side (same 128B line).
__device__ __forceinline__ void stage_tile(const unsigned char* __restrict__ gsrc,
                                           int ldk, unsigned char* lds, int w, int lane)
{
#pragma unroll
    for (int c = 0; c < 4; ++c) {
        int q  = (w * 4 + c) * 64 + lane;        // 0..1023
        int gr = q >> 3;
        int gq = (q & 7) ^ (gr & 7);
        const unsigned char* g = gsrc + (size_t)gr * ldk + gq * 16;
        async_copy16(g, lds + (w * 4 + c) * 1024);
    }
}

// Load a 32-row A/B fragment for mfma_scale_32x32x64: lane holds row rbase+m32,
// k-bytes (s*64 + hi*32) .. +32 (two swizzled 16B chunks). Any consistent
// K-bijection is correct since A and B use the same loader.
__device__ __forceinline__ int8v load_frag(const unsigned char* lds, int rbase,
                                           int m32, int hi, int s)
{
    int R  = rbase + m32;
    int sw = R & 7;
    int c0 = (s * 4 + hi * 2)     ^ sw;
    int c1 = (s * 4 + hi * 2 + 1) ^ sw;
    int4 lo = *(const int4*)(lds + R * 128 + c0 * 16);
    int4 hv = *(const int4*)(lds + R * 128 + c1 * 16);
    int8v f;
    f[0] = lo.x; f[1] = lo.y; f[2] = lo.z; f[3] = lo.w;
    f[4] = hv.x; f[5] = hv.y; f[6] = hv.z; f[7] = hv.w;
    return f;
}

#define MFMA_SC(a, b, c) __builtin_amdgcn_mfma_scale_f32_32x32x64_f8f6f4( \
    (a), (b), (c), 0, 0, 0, SCALE1, 0, SCALE1)

// ---------------- fused tile kernel: gram mask + sim + mine + store ----------------
__global__ __launch_bounds__(256) void tile_kernel(
    const unsigned char* __restrict__ imgF,
    const unsigned char* __restrict__ txtF,
    const unsigned char* __restrict__ cptF,
    float* __restrict__ pmax, unsigned char* __restrict__ ppos,
    unsigned char* __restrict__ pneg,
    unsigned short* __restrict__ simM)
{
    __shared__ unsigned char As[128 * 128];   // 16 KB
    __shared__ unsigned char Bs[128 * 128];   // 16 KB
    __shared__ float eps_max[2][128];
    __shared__ unsigned int eps_pos[2][128];
    __shared__ unsigned int eps_neg[2][128];

    const int tid  = threadIdx.x;
    const int lane = tid & 63;
    const int w    = tid >> 6;      // wave 0..3
    const int wr   = w >> 1;        // wave row (0..1) -> rows wr*64..+63
    const int wc   = w & 1;         // wave col (0..1) -> cols wc*64..+63
    const int m32  = lane & 31;
    const int hi   = lane >> 5;

    const int ct = blockIdx.x, rt = blockIdx.y;
    const int r0 = rt * 128, c0 = ct * 128;

    f32x16 acc[2][2];
#pragma unroll
    for (int mt = 0; mt < 2; ++mt)
#pragma unroll
        for (int nt = 0; nt < 2; ++nt)
#pragma unroll
            for (int r = 0; r < 16; ++r)
                acc[mt][nt][r] = 0.f;

    // -------- gram = concept @ concept^T, K = 256 (2 staged steps) --------
    for (int kb = 0; kb < C_SZ; kb += 128) {
        __syncthreads();
        stage_tile(cptF + (size_t)r0 * C_SZ + kb, C_SZ, As, w, lane);
        stage_tile(cptF + (size_t)c0 * C_SZ + kb, C_SZ, Bs, w, lane);
        __syncthreads();
#pragma unroll
        for (int s = 0; s < 2; ++s) {
            int8v a0 = load_frag(As, wr * 64,      m32, hi, s);
            int8v a1 = load_frag(As, wr * 64 + 32, m32, hi, s);
            int8v b0 = load_frag(Bs, wc * 64,      m32, hi, s);
            int8v b1 = load_frag(Bs, wc * 64 + 32, m32, hi, s);
            acc[0][0] = MFMA_SC(a0, b0, acc[0][0]);
            acc[0][1] = MFMA_SC(a0, b1, acc[0][1]);
            acc[1][0] = MFMA_SC(a1, b0, acc[1][0]);
            acc[1][1] = MFMA_SC(a1, b1, acc[1][1]);
        }
    }

    // pos bits: gram > 0.5 and off-diagonal. bit = (mt*2+nt)*16 + r
    // C/D map (m74/m101, dtype-indep m121-128): col = lane&31,
    // row = (r&3) + 8*(r>>2) + 4*(lane>>5)
    unsigned long long posbits = 0ull;
#pragma unroll
    for (int mt = 0; mt < 2; ++mt)
#pragma unroll
        for (int nt = 0; nt < 2; ++nt)
#pragma unroll
            for (int r = 0; r < 16; ++r) {
                int grow = r0 + wr * 64 + mt * 32 + (r & 3) + 8 * (r >> 2) + 4 * hi;
                int gcol = c0 + wc * 64 + nt * 32 + m32;
                int pos = (acc[mt][nt][r] > THRESH) & (grow != gcol);
                posbits |= ((unsigned long long)pos) << ((mt * 2 + nt) * 16 + r);
            }

    // -------- sim = image @ text^T, K = 1024 (8 staged steps) --------
#pragma unroll
    for (int mt = 0; mt < 2; ++mt)
#pragma unroll
        for (int nt = 0; nt < 2; ++nt)
#pragma unroll
            for (int r = 0; r < 16; ++r)
                acc[mt][nt][r] = 0.f;

    for (int kb = 0; kb < D_SZ; kb += 128) {
        __syncthreads();
        stage_tile(imgF + (size_t)r0 * D_SZ + kb, D_SZ, As, w, lane);
        stage_tile(txtF + (size_t)c0 * D_SZ + kb, D_SZ, Bs, w, lane);
        __syncthreads();
#pragma unroll
        for (int s = 0; s < 2; ++s) {
            int8v a0 = load_frag(As, wr * 64,      m32, hi, s);
            int8v a1 = load_frag(As, wr * 64 + 32, m32, hi, s);
            int8v b0 = load_frag(Bs, wc * 64,      m32, hi, s);
            int8v b1 = load_frag(Bs, wc * 64 + 32, m32, hi, s);
            acc[0][0] = MFMA_SC(a0, b0, acc[0][0]);
            acc[0][1] = MFMA_SC(a0, b1, acc[0][1]);
            acc[1][0] = MFMA_SC(a1, b0, acc[1][0]);
            acc[1][1] = MFMA_SC(a1, b1, acc[1][1]);
        }
    }

    // -------- epilogue: mine neg-max / any-pos / any-neg, store masked sim --------
#pragma unroll
    for (int mt = 0; mt < 2; ++mt)
#pragma unroll
        for (int r = 0; r < 16; ++r) {
            int rloc = mt * 32 + (r & 3) + 8 * (r >> 2) + 4 * hi;   // 0..63 in wave rows
            int grow = r0 + wr * 64 + rloc;
            float rowm = -FLT_MAX;
            int rp = 0, rn = 0;
#pragma unroll
            for (int nt = 0; nt < 2; ++nt) {
                int bit  = (mt * 2 + nt) * 16 + r;
                int pos  = (int)((posbits >> bit) & 1ull);
                int gcol = c0 + wc * 64 + nt * 32 + m32;
                int diag = (grow == gcol);
                int neg  = (!pos) & (!diag);
                float s  = acc[mt][nt][r];
                rowm = neg ? fmaxf(rowm, s) : rowm;
                rp |= pos; rn |= neg;
                // masked sim: pos ? bf16(sim) : +inf (sentinel encodes the mask)
                float mv = pos ? s : __builtin_inff();
                __hip_bfloat16 hb = __float2bfloat16(mv);
                simM[(size_t)grow * B_SZ + gcol] = *(unsigned short*)&hb;
            }
            // reduce across 32 lanes of this half (same rows, different cols)
#pragma unroll
            for (int m = 1; m < 32; m <<= 1) {
                rowm = fmaxf(rowm, __shfl_xor(rowm, m));
                rp |= __shfl_xor(rp, m);
                rn |= __shfl_xor(rn, m);
            }
            if (m32 == 0) {     // lane 0 (hi=0) and lane 32 (hi=1): different rows
                int rl = wr * 64 + rloc;
                eps_max[wc][rl] = rowm;
                eps_pos[wc][rl] = (unsigned int)rp;
                eps_neg[wc][rl] = (unsigned int)rn;
            }
        }
    __syncthreads();
    if (tid < 128) {
        float m = fmaxf(eps_max[0][tid], eps_max[1][tid]);
        unsigned int p = eps_pos[0][tid] | eps_pos[1][tid];
        unsigned int n = eps_neg[0][tid] | eps_neg[1][tid];
        size_t idx = (size_t)ct * B_SZ + (r0 + tid);
        pmax[idx] = m;
        ppos[idx] = (unsigned char)(p ? 1 : 0);
        pneg[idx] = (unsigned char)(n ? 1 : 0);
    }
}

// ---------------- per-row partial reduce ----------------
__global__ __launch_bounds__(256) void reduce_kernel(
    const float* __restrict__ pmax, const unsigned char* __restrict__ ppos,
    const unsigned char* __restrict__ pneg,
    float* __restrict__ hn, unsigned char* __restrict__ validv)
{
    int row = blockIdx.x * blockDim.x + threadIdx.x;
    if (row >= B_SZ) return;
    float m = -FLT_MAX;
    int hp = 0, hnn = 0;
    for (int ct = 0; ct < 64; ++ct) {
        size_t idx = (size_t)ct * B_SZ + row;
        m = fmaxf(m, pmax[idx]);
        hp  |= ppos[idx];
        hnn |= pneg[idx];
    }
    int valid = (hp && hnn) ? 1 : 0;
    hn[row] = valid ? m : 0.0f;
    validv[row] = (unsigned char)valid;
}

// ---------------- streaming hinge over masked sim ----------------
__global__ __launch_bounds__(256) void hinge_kernel(
    const unsigned short* __restrict__ simM,
    const float* __restrict__ hn, const unsigned char* __restrict__ validv,
    float* __restrict__ accsum, unsigned int* __restrict__ acccnt)
{
    __shared__ float redS[4];
    __shared__ unsigned int redC[4];
    const size_t N8 = (size_t)B_SZ * B_SZ / 8;   // 16B (8 bf16) chunks
    const size_t stride = (size_t)gridDim.x * blockDim.x;
    float lsum = 0.f;
    unsigned int lcnt = 0;
    for (size_t i = (size_t)blockIdx.x * blockDim.x + threadIdx.x; i < N8; i += stride) {
        int row = (int)(i >> 10);                 // 1024 chunks per row
        float hv = hn[row];
        int v = (int)validv[row];
        ushort4 c0 = ((const ushort4*)simM)[i * 2];
        ushort4 c1 = ((const ushort4*)simM)[i * 2 + 1];
        unsigned short e[8] = {c0.x, c0.y, c0.z, c0.w, c1.x, c1.y, c1.z, c1.w};
#pragma unroll
        for (int j = 0; j < 8; ++j) {
            int on = (e[j] != INF_BF16_BITS) & v;
            float s = __uint_as_float(((unsigned int)e[j]) << 16);
            float h = fmaxf(MARGIN - s + hv, 0.f);
            lsum += on ? h : 0.f;
            lcnt += (unsigned int)on;
        }
    }
    const int lane = threadIdx.x & 63;
    const int w    = threadIdx.x >> 6;
#pragma unroll
    for (int off = 32; off > 0; off >>= 1) {
        lsum += __shfl_down(lsum, off);
        lcnt += (unsigned int)__shfl_down((int)lcnt, off);
    }
    if (lane == 0) { redS[w] = lsum; redC[w] = lcnt; }
    __syncthreads();
    if (threadIdx.x == 0) {
        atomicAdd(accsum, redS[0] + redS[1] + redS[2] + redS[3]);
        atomicAdd(acccnt, redC[0] + redC[1] + redC[2] + redC[3]);
    }
}

// ---------------- finalize ----------------
__global__ void final_kernel(const float* __restrict__ accsum,
                             const unsigned int* __restrict__ acccnt,
                             float* __restrict__ out)
{
    float s = accsum[0];
    unsigned int c = acccnt[0];
    out[0] = (c > 0) ? (s / (float)c) : 0.0f;
}

extern "C" void kernel_launch(void* const* d_in, const int* in_sizes, int n_in,
                              void* d_out, int out_size, void* d_ws, size_t ws_size,
                              hipStream_t stream)
{
    const float* img = (const float*)d_in[0];   // [8192,1024]
    const float* txt = (const float*)d_in[1];   // [8192,1024]
    const float* cpt = (const float*)d_in[2];   // [8192,256]
    float* out = (float*)d_out;

    char* ws = (char*)d_ws;
    unsigned char* imgF  = (unsigned char*)(ws + OFF_IMG);
    unsigned char* txtF  = (unsigned char*)(ws + OFF_TXT);
    unsigned char* cptF  = (unsigned char*)(ws + OFF_CPT);
    float* hn            = (float*)(ws + OFF_HN);
    unsigned char* valid = (unsigned char*)(ws + OFF_VALID);
    float* pmax          = (float*)(ws + OFF_PMAX);
    unsigned char* ppos  = (unsigned char*)(ws + OFF_PPOS);
    unsigned char* pneg  = (unsigned char*)(ws + OFF_PNEG);
    float* accsum        = (float*)(ws + OFF_ACC);
    unsigned int* acccnt = (unsigned int*)(ws + OFF_ACC + 4);
    unsigned short* simM = (unsigned short*)(ws + OFF_SIM);

    hipMemsetAsync(ws + OFF_ACC, 0, 16, stream);

    // fp32 -> fp8: (8192*1024*2 + 8192*256) / 8 = 2,359,296 threads
    conv_kernel<<<9216, 256, 0, stream>>>(img, txt, cpt, imgF, txtF, cptF);

    dim3 grid(64, 64);
    tile_kernel<<<grid, 256, 0, stream>>>(imgF, txtF, cptF, pmax, ppos, pneg, simM);
    reduce_kernel<<<32, 256, 0, stream>>>(pmax, ppos, pneg, hn, valid);
    hinge_kernel<<<2048, 256, 0, stream>>>(simM, hn, valid, accsum, acccnt);
    final_kernel<<<1, 1, 0, stream>>>(accsum, acccnt, out);
}